// Round 3
// baseline (209.729 us; speedup 1.0000x reference)
//
#include <hip/hip_runtime.h>

#define NB 4096   // batch rows
#define NT 256    // time points

typedef __bf16 bf16x8 __attribute__((ext_vector_type(8)));
typedef __bf16 bf16x4 __attribute__((ext_vector_type(4)));
typedef float f32x4 __attribute__((ext_vector_type(4)));
typedef unsigned int u32;
typedef unsigned int u32x4 __attribute__((ext_vector_type(4)));
typedef unsigned long long u64;

static __device__ __forceinline__ f32x4 mfma16(bf16x8 a, bf16x8 b, f32x4 c) {
  return __builtin_amdgcn_mfma_f32_16x16x32_bf16(a, b, c, 0, 0, 0);
}

// tanh(x) = 1 - 2/(1+e^{2x}); no clamp needed: exp2(+inf)=inf -> rcp=0 -> 1,
// exp2(-inf)=0 -> 1-2 = -1. Both saturate to the correct limit.
static __device__ __forceinline__ float ftanh(float x) {
  float e = __builtin_amdgcn_exp2f(x * 2.885390082f);
  return __builtin_fmaf(-2.0f, __builtin_amdgcn_rcpf(e + 1.0f), 1.0f);
}

static __device__ __forceinline__ u64 pack4(const f32x4& v) {
  bf16x4 p;
  p[0] = (__bf16)ftanh(v[0]);
  p[1] = (__bf16)ftanh(v[1]);
  p[2] = (__bf16)ftanh(v[2]);
  p[3] = (__bf16)ftanh(v[3]);
  return __builtin_bit_cast(u64, p);
}

static __device__ __forceinline__ bf16x8 frag2(u64 lo, u64 hi) {
  u32x4 v;
  v[0] = (u32)lo; v[1] = (u32)(lo >> 32);
  v[2] = (u32)hi; v[3] = (u32)(hi >> 32);
  return __builtin_bit_cast(bf16x8, v);
}

// Block = 4 waves (one per SIMD), 16 batch rows, all 255 steps.
// L1 split across waves (wave w -> out-tile w); h1 exchanged via LDS
// (double-buffered, ONE barrier per step). L2 + L3 computed fully
// redundantly per wave -- the sigma k-slot bijection
//   sigma(kf,g,j) = 32*kf + 16*(j>>2) + 4*g + (j&3)
// makes the D->B relayout between layers pure same-lane register renaming.
__global__ __launch_bounds__(256) void sde_kernel(
    const float* __restrict__ z0, const float* __restrict__ ts,
    const float* __restrict__ noise, const float* __restrict__ W1,
    const float* __restrict__ b1, const float* __restrict__ W2,
    const float* __restrict__ b2, const float* __restrict__ W3,
    const float* __restrict__ b3, const float* __restrict__ log_std,
    float* __restrict__ out) {
  (void)ts;
  __shared__ u64 h1x[2][4][64];  // [t&1][wave][lane], double-buffered

  const int lane = threadIdx.x & 63;
  const int wv = threadIdx.x >> 6;   // wave id 0..3 (== L1 out-tile)
  const int c = lane & 15;           // batch row within tile
  const int g = lane >> 4;           // lane group 0..3
  const int R = blockIdx.x * 16 + c; // this lane's batch row

  // ---- stationary weight A-fragments ----
  bf16x8 a1;        // W1' out-tile wv: [16 out][32 in]   (split)
  bf16x8 a2[4][2];  // W2^T full:       [64 out][64 in]   (redundant)
  bf16x8 a3[2][2];  // W3^T full:       [32 out][64 in]   (redundant)
#pragma unroll
  for (int j = 0; j < 8; ++j) {
    int k = 16 * (j >> 2) + 4 * g + (j & 3);          // sigma, kf=0
    a1[j] = (__bf16)W1[(1 + k) * 64 + 16 * wv + c];   // skip t-row 0
  }
#pragma unroll
  for (int ot = 0; ot < 4; ++ot)
#pragma unroll
    for (int kf = 0; kf < 2; ++kf)
#pragma unroll
      for (int j = 0; j < 8; ++j) {
        int k = 32 * kf + 16 * (j >> 2) + 4 * g + (j & 3);
        a2[ot][kf][j] = (__bf16)W2[k * 64 + 16 * ot + c];
      }
#pragma unroll
  for (int ot = 0; ot < 2; ++ot)
#pragma unroll
    for (int kf = 0; kf < 2; ++kf)
#pragma unroll
      for (int j = 0; j < 8; ++j) {
        int k = 32 * kf + 16 * (j >> 2) + 4 * g + (j & 3);
        a3[ot][kf][j] = (__bf16)W3[k * 32 + 16 * ot + c];
      }

  // ---- per-lane constants in D-layout: elem r <-> d = 16*ot + 4*g + r ----
  f32x4 b1v, w1r0;           // L1: own tile only
#pragma unroll
  for (int r = 0; r < 4; ++r) {
    int d = 16 * wv + 4 * g + r;
    b1v[r] = b1[d];
    w1r0[r] = W1[d];         // W1 row 0 (t coefficient)
  }
  f32x4 b2v[4];              // L2: all tiles (redundant compute)
#pragma unroll
  for (int ot = 0; ot < 4; ++ot)
#pragma unroll
    for (int r = 0; r < 4; ++r) b2v[ot][r] = b2[16 * ot + 4 * g + r];
  f32x4 b3v[2], stdv[2];
#pragma unroll
  for (int ot = 0; ot < 2; ++ot)
#pragma unroll
    for (int r = 0; r < 4; ++r) {
      int d = 16 * ot + 4 * g + r;
      b3v[ot][r] = b3[d];
      stdv[ot][r] = expf(log_std[d]);
    }

  // ---- state init: every wave holds the FULL y for its 16 rows ----
  f32x4 y0v = *reinterpret_cast<const f32x4*>(z0 + (size_t)R * 32 + 4 * g);
  f32x4 y1v = *reinterpret_cast<const f32x4*>(z0 + (size_t)R * 32 + 16 + 4 * g);
  if (wv == 0)
    *reinterpret_cast<f32x4*>(out + (size_t)R * 32 + 4 * g) = y0v;
  if (wv == 1)
    *reinterpret_cast<f32x4*>(out + (size_t)R * 32 + 16 + 4 * g) = y1v;

  bf16x8 yb;  // y^T B-fragment: slot j -> dim 16*(j>>2)+4*g+(j&3)
#pragma unroll
  for (int j = 0; j < 8; ++j)
    yb[j] = (__bf16)((j >> 2) ? y1v[j & 3] : y0v[j & 3]);

  // noise prefetch (one step ahead)
  const float* nzp0 = noise + ((size_t)0 * NB + R) * 32 + 4 * g;
  f32x4 nz0 = *reinterpret_cast<const f32x4*>(nzp0);
  f32x4 nz1 = *reinterpret_cast<const f32x4*>(nzp0 + 16);

  for (int t = 0; t < NT - 1; ++t) {
    // prefetch next step's noise
    int tn = (t < NT - 2) ? (t + 1) : (NT - 2);
    const float* nzp = noise + ((size_t)tn * NB + R) * 32 + 4 * g;
    f32x4 nzn0 = *reinterpret_cast<const f32x4*>(nzp);
    f32x4 nzn1 = *reinterpret_cast<const f32x4*>(nzp + 16);

    float tcur = (float)t * 0.005f;               // == ts[t] bit-exact
    float dtv = (float)(t + 1) * 0.005f - tcur;   // == ts[t+1]-ts[t]
    float sdt = sqrtf(dtv);

    // ---- phase A: layer 1, this wave's 16 hidden outs -> LDS ----
    f32x4 d1 = mfma16(a1, yb, b1v + tcur * w1r0);
    h1x[t & 1][wv][lane] = pack4(d1);  // tanh + bf16 pack
    __syncthreads();

    // ---- phase B: full L2 + L3 redundantly per wave (register-local) ----
    u64 q0 = h1x[t & 1][0][lane], q1 = h1x[t & 1][1][lane];
    u64 q2 = h1x[t & 1][2][lane], q3 = h1x[t & 1][3][lane];
    bf16x8 hb0 = frag2(q0, q1);
    bf16x8 hb1 = frag2(q2, q3);

    f32x4 d2[4];
#pragma unroll
    for (int ot = 0; ot < 4; ++ot)
      d2[ot] = mfma16(a2[ot][1], hb1, mfma16(a2[ot][0], hb0, b2v[ot]));

    bf16x8 gb0, gb1;  // sigma repack: lane-local, no LDS
#pragma unroll
    for (int j = 0; j < 8; ++j) {
      gb0[j] = (__bf16)ftanh(d2[(j >> 2)][j & 3]);
      gb1[j] = (__bf16)ftanh(d2[2 + (j >> 2)][j & 3]);
    }

    f32x4 d30 = mfma16(a3[0][1], gb1, mfma16(a3[0][0], gb0, b3v[0]));
    f32x4 d31 = mfma16(a3[1][1], gb1, mfma16(a3[1][0], gb0, b3v[1]));

    // ---- Euler-Maruyama update + store ----
    y0v = y0v + d30 * dtv + (stdv[0] * sdt) * nz0;
    y1v = y1v + d31 * dtv + (stdv[1] * sdt) * nz1;

    float* op = out + ((size_t)(t + 1) * NB + R) * 32 + 4 * g;
    if (wv == 0) *reinterpret_cast<f32x4*>(op) = y0v;
    if (wv == 1) *reinterpret_cast<f32x4*>(op + 16) = y1v;

#pragma unroll
    for (int j = 0; j < 8; ++j)
      yb[j] = (__bf16)((j >> 2) ? y1v[j & 3] : y0v[j & 3]);

    nz0 = nzn0;
    nz1 = nzn1;
  }
}

extern "C" void kernel_launch(void* const* d_in, const int* in_sizes, int n_in,
                              void* d_out, int out_size, void* d_ws, size_t ws_size,
                              hipStream_t stream) {
  (void)in_sizes; (void)n_in; (void)out_size; (void)d_ws; (void)ws_size;
  const float* z0   = (const float*)d_in[0];
  const float* ts   = (const float*)d_in[1];
  const float* nz   = (const float*)d_in[2];
  const float* W1   = (const float*)d_in[3];
  const float* b1   = (const float*)d_in[4];
  const float* W2   = (const float*)d_in[5];
  const float* b2   = (const float*)d_in[6];
  const float* W3   = (const float*)d_in[7];
  const float* b3   = (const float*)d_in[8];
  const float* lstd = (const float*)d_in[9];
  float* out = (float*)d_out;
  hipLaunchKernelGGL(sde_kernel, dim3(NB / 16), dim3(256), 0, stream,
                     z0, ts, nz, W1, b1, W2, b2, W3, b3, lstd, out);
}

// Round 4
// 185.353 us; speedup vs baseline: 1.1315x; 1.1315x over previous
//
#include <hip/hip_runtime.h>

#define NB 4096   // batch rows
#define NT 256    // time points

typedef __bf16 bf16x8 __attribute__((ext_vector_type(8)));
typedef __bf16 bf16x4 __attribute__((ext_vector_type(4)));
typedef float f32x4 __attribute__((ext_vector_type(4)));
typedef unsigned int u32;
typedef unsigned int u32x4 __attribute__((ext_vector_type(4)));
typedef unsigned long long u64;

static __device__ __forceinline__ f32x4 mfma16(bf16x8 a, bf16x8 b, f32x4 c) {
  return __builtin_amdgcn_mfma_f32_16x16x32_bf16(a, b, c, 0, 0, 0);
}

// Raw barrier: LDS-drain only, does NOT drain vmcnt -> global prefetch
// loads stay in flight across it (8-phase template pattern, m194-m201).
#define LDS_BARRIER() asm volatile("s_waitcnt lgkmcnt(0)\n\ts_barrier" ::: "memory")

// tanh(x) = 1 - 2/(1+e^{2x}); no clamp: exp2(+inf)=inf -> rcp=0 -> +1,
// exp2(-inf)=0 -> -1. Saturates to the correct limits.
static __device__ __forceinline__ float ftanh(float x) {
  float e = __builtin_amdgcn_exp2f(x * 2.885390082f);
  return __builtin_fmaf(-2.0f, __builtin_amdgcn_rcpf(e + 1.0f), 1.0f);
}

static __device__ __forceinline__ u64 pack4(const f32x4& v) {
  bf16x4 p;
  p[0] = (__bf16)ftanh(v[0]);
  p[1] = (__bf16)ftanh(v[1]);
  p[2] = (__bf16)ftanh(v[2]);
  p[3] = (__bf16)ftanh(v[3]);
  return __builtin_bit_cast(u64, p);
}

static __device__ __forceinline__ bf16x8 frag2(u64 lo, u64 hi) {
  u32x4 v;
  v[0] = (u32)lo; v[1] = (u32)(lo >> 32);
  v[2] = (u32)hi; v[3] = (u32)(hi >> 32);
  return __builtin_bit_cast(bf16x8, v);
}

// Block = 4 waves (one per SIMD), 16 batch rows, all 255 steps.
// Wave w owns hidden out-tile w for L1 and L2; h1/h2 exchanged via LDS with
// raw s_barrier (lgkm-drain only, vmcnt NOT drained -> noise prefetch
// survives). L3 redundant per wave -> y stays wave-local.
// sigma(kf,g,j) = 32*kf + 16*(j>>2) + 4*g + (j&3): wave w's D-frag elem r
// == B-frag[kf=w>>1][j=4*(w&1)+r] at the SAME lane -> exchange is one u64
// write + 4 u64 reads per layer, conflict-free (8B stride = free 2-way).
__global__ __launch_bounds__(256) void sde_kernel(
    const float* __restrict__ z0, const float* __restrict__ ts,
    const float* __restrict__ noise, const float* __restrict__ W1,
    const float* __restrict__ b1, const float* __restrict__ W2,
    const float* __restrict__ b2, const float* __restrict__ W3,
    const float* __restrict__ b3, const float* __restrict__ log_std,
    float* __restrict__ out) {
  (void)ts;
  __shared__ u64 h1x[4][64];
  __shared__ u64 h2x[4][64];

  const int lane = threadIdx.x & 63;
  const int wv = threadIdx.x >> 6;   // wave id 0..3 (== out-tile for L1/L2)
  const int c = lane & 15;           // batch row within tile
  const int g = lane >> 4;           // lane group 0..3
  const int R = blockIdx.x * 16 + c; // this lane's batch row

  // ---- stationary weight A-fragments (per wave) ----
  bf16x8 a1;        // W1' out-tile wv : [16 out][32 in]
  bf16x8 a2[2];     // W2^T out-tile wv: [16 out][64 in], 2 K-frags
  bf16x8 a3[2][2];  // W3^T full:        [32 out][64 in]  (redundant all waves)
#pragma unroll
  for (int j = 0; j < 8; ++j) {
    int k = 16 * (j >> 2) + 4 * g + (j & 3);            // sigma, kf=0
    a1[j] = (__bf16)W1[(1 + k) * 64 + 16 * wv + c];     // skip t-row 0
  }
#pragma unroll
  for (int kf = 0; kf < 2; ++kf)
#pragma unroll
    for (int j = 0; j < 8; ++j) {
      int k = 32 * kf + 16 * (j >> 2) + 4 * g + (j & 3);
      a2[kf][j] = (__bf16)W2[k * 64 + 16 * wv + c];
    }
#pragma unroll
  for (int ot = 0; ot < 2; ++ot)
#pragma unroll
    for (int kf = 0; kf < 2; ++kf)
#pragma unroll
      for (int j = 0; j < 8; ++j) {
        int k = 32 * kf + 16 * (j >> 2) + 4 * g + (j & 3);
        a3[ot][kf][j] = (__bf16)W3[k * 32 + 16 * ot + c];
      }

  // ---- per-lane constants, D-layout: elem r <-> d = 16*ot + 4*g + r ----
  f32x4 b1v, w1r0, b2v;
#pragma unroll
  for (int r = 0; r < 4; ++r) {
    int d = 16 * wv + 4 * g + r;
    b1v[r] = b1[d];
    w1r0[r] = W1[d];   // W1 row 0 (t coefficient)
    b2v[r] = b2[d];
  }
  f32x4 b3v[2], stdv[2];
#pragma unroll
  for (int ot = 0; ot < 2; ++ot)
#pragma unroll
    for (int r = 0; r < 4; ++r) {
      int d = 16 * ot + 4 * g + r;
      b3v[ot][r] = b3[d];
      stdv[ot][r] = expf(log_std[d]);
    }

  // ---- state init: every wave holds the FULL y for its 16 rows ----
  f32x4 y0v = *reinterpret_cast<const f32x4*>(z0 + (size_t)R * 32 + 4 * g);
  f32x4 y1v = *reinterpret_cast<const f32x4*>(z0 + (size_t)R * 32 + 16 + 4 * g);
  if (wv == 0)
    *reinterpret_cast<f32x4*>(out + (size_t)R * 32 + 4 * g) = y0v;
  if (wv == 1)
    *reinterpret_cast<f32x4*>(out + (size_t)R * 32 + 16 + 4 * g) = y1v;

  bf16x8 yb;  // y^T B-fragment: slot j -> dim 16*(j>>2)+4*g+(j&3)
#pragma unroll
  for (int j = 0; j < 8; ++j)
    yb[j] = (__bf16)((j >> 2) ? y1v[j & 3] : y0v[j & 3]);

  // noise prefetch (one step ahead)
  const float* nzp0 = noise + ((size_t)0 * NB + R) * 32 + 4 * g;
  f32x4 nz0 = *reinterpret_cast<const f32x4*>(nzp0);
  f32x4 nz1 = *reinterpret_cast<const f32x4*>(nzp0 + 16);

  for (int t = 0; t < NT - 1; ++t) {
    // prefetch next step's noise; stays in flight across BOTH barriers,
    // vmcnt-waited only at next iteration's y-update (~1.7 steps later)
    int tn = (t < NT - 2) ? (t + 1) : (NT - 2);
    const float* nzp = noise + ((size_t)tn * NB + R) * 32 + 4 * g;
    f32x4 nzn0 = *reinterpret_cast<const f32x4*>(nzp);
    f32x4 nzn1 = *reinterpret_cast<const f32x4*>(nzp + 16);

    float tcur = (float)t * 0.005f;               // == ts[t] bit-exact
    float dtv = (float)(t + 1) * 0.005f - tcur;   // == ts[t+1]-ts[t]
    float sdt = sqrtf(dtv);

    // ---- phase A: layer 1, this wave's 16 hidden outs -> LDS ----
    f32x4 d1 = mfma16(a1, yb, b1v + tcur * w1r0);
    h1x[wv][lane] = pack4(d1);  // tanh + bf16 pack
    LDS_BARRIER();

    // ---- phase B: layer 2, this wave's 16 hidden outs -> LDS ----
    u64 q0 = h1x[0][lane], q1 = h1x[1][lane];
    u64 q2 = h1x[2][lane], q3 = h1x[3][lane];
    bf16x8 hb0 = frag2(q0, q1);
    bf16x8 hb1 = frag2(q2, q3);
    f32x4 d2 = mfma16(a2[1], hb1, mfma16(a2[0], hb0, b2v));
    h2x[wv][lane] = pack4(d2);
    LDS_BARRIER();

    // ---- phase C: layer 3 (redundant per wave) + EM update ----
    u64 p0 = h2x[0][lane], p1 = h2x[1][lane];
    u64 p2 = h2x[2][lane], p3 = h2x[3][lane];
    bf16x8 gb0 = frag2(p0, p1);
    bf16x8 gb1 = frag2(p2, p3);
    f32x4 d30 = mfma16(a3[0][1], gb1, mfma16(a3[0][0], gb0, b3v[0]));
    f32x4 d31 = mfma16(a3[1][1], gb1, mfma16(a3[1][0], gb0, b3v[1]));

    y0v = y0v + d30 * dtv + (stdv[0] * sdt) * nz0;
    y1v = y1v + d31 * dtv + (stdv[1] * sdt) * nz1;

    float* op = out + ((size_t)(t + 1) * NB + R) * 32 + 4 * g;
    if (wv == 0) *reinterpret_cast<f32x4*>(op) = y0v;
    if (wv == 1) *reinterpret_cast<f32x4*>(op + 16) = y1v;

#pragma unroll
    for (int j = 0; j < 8; ++j)
      yb[j] = (__bf16)((j >> 2) ? y1v[j & 3] : y0v[j & 3]);

    nz0 = nzn0;
    nz1 = nzn1;
  }
}

extern "C" void kernel_launch(void* const* d_in, const int* in_sizes, int n_in,
                              void* d_out, int out_size, void* d_ws, size_t ws_size,
                              hipStream_t stream) {
  (void)in_sizes; (void)n_in; (void)out_size; (void)d_ws; (void)ws_size;
  const float* z0   = (const float*)d_in[0];
  const float* ts   = (const float*)d_in[1];
  const float* nz   = (const float*)d_in[2];
  const float* W1   = (const float*)d_in[3];
  const float* b1   = (const float*)d_in[4];
  const float* W2   = (const float*)d_in[5];
  const float* b2   = (const float*)d_in[6];
  const float* W3   = (const float*)d_in[7];
  const float* b3   = (const float*)d_in[8];
  const float* lstd = (const float*)d_in[9];
  float* out = (float*)d_out;
  hipLaunchKernelGGL(sde_kernel, dim3(NB / 16), dim3(256), 0, stream,
                     z0, ts, nz, W1, b1, W2, b2, W3, b3, lstd, out);
}